// Round 1
// baseline (612.210 us; speedup 1.0000x reference)
//
#include <hip/hip_runtime.h>
#include <math.h>

// Problem constants (match reference)
#define NV 8192
#define EV 49152
#define KK 15625

__device__ __forceinline__ void edge_frac(const float* __restrict__ pseudo, int e,
                                          float f[3], int lo[3]) {
#pragma unroll
    for (int j = 0; j < 3; ++j) {
        float v = pseudo[e * 3 + j] * 24.0f;
        float fl = floorf(v);
        int l = (int)fl;
        l = l < 0 ? 0 : (l > 23 ? 23 : l);
        lo[j] = l;
        f[j] = v - (float)l;
    }
}

__global__ void transform_kernel(const float* __restrict__ x, float* __restrict__ h0) {
    int n = blockIdx.x * blockDim.x + threadIdx.x;
    if (n >= NV) return;
    const float LC = -0.22703196f, UC = 0.36853024f;
    const float LM = 1.2585511f, UM = 1.648841f;
    const float R = 10.0f;
    float t0 = (x[n * 2 + 0] - LC) / (UC - LC) * (2.0f * R) - R;
    float t1 = (x[n * 2 + 1] - LM) / (UM - LM) * (2.0f * R) - R;
    h0[n * 2 + 0] = fminf(fmaxf(t0, -R), R);
    h0[n * 2 + 1] = fminf(fmaxf(t1, -R), R);
}

__global__ void hist_kernel(const float* __restrict__ pseudo, int* __restrict__ counts) {
    int e = blockIdx.x * blockDim.x + threadIdx.x;
    if (e >= EV) return;
    float f[3]; int lo[3];
    edge_frac(pseudo, e, f, lo);
#pragma unroll
    for (int s = 0; s < 8; ++s) {
        int wi = (lo[0] + (s & 1)) + 25 * (lo[1] + ((s >> 1) & 1)) + 625 * (lo[2] + ((s >> 2) & 1));
        atomicAdd(&counts[wi], 1);
    }
}

// single-block exclusive scan over KK bins
__global__ void scan_kernel(const int* __restrict__ counts, int* __restrict__ offsets,
                            int* __restrict__ cursor) {
    __shared__ int sums[256];
    const int CH = 62;  // 256*62 = 15872 >= 15625
    int t = threadIdx.x;
    int base = t * CH;
    int s = 0;
    for (int i = 0; i < CH; ++i) {
        int idx = base + i;
        if (idx < KK) s += counts[idx];
    }
    sums[t] = s;
    __syncthreads();
    for (int d = 1; d < 256; d <<= 1) {
        int v = (t >= d) ? sums[t - d] : 0;
        __syncthreads();
        sums[t] += v;
        __syncthreads();
    }
    int run = (t > 0) ? sums[t - 1] : 0;
    for (int i = 0; i < CH; ++i) {
        int idx = base + i;
        if (idx < KK) {
            offsets[idx] = run;
            cursor[idx] = run;
            run += counts[idx];
        }
    }
    if (t == 255) offsets[KK] = run;
}

__global__ void scatter_kernel(const float* __restrict__ pseudo, int* __restrict__ cursor,
                               int* __restrict__ pair_e, float* __restrict__ pair_b) {
    int e = blockIdx.x * blockDim.x + threadIdx.x;
    if (e >= EV) return;
    float f[3]; int lo[3];
    edge_frac(pseudo, e, f, lo);
#pragma unroll
    for (int s = 0; s < 8; ++s) {
        float b = ((s & 1) ? f[0] : 1.0f - f[0]) *
                  (((s >> 1) & 1) ? f[1] : 1.0f - f[1]) *
                  (((s >> 2) & 1) ? f[2] : 1.0f - f[2]);
        int wi = (lo[0] + (s & 1)) + 25 * (lo[1] + ((s >> 1) & 1)) + 625 * (lo[2] + ((s >> 2) & 1));
        int pos = atomicAdd(&cursor[wi], 1);
        pair_e[pos] = e;
        pair_b[pos] = b;
    }
}

// One wave per kernel-index k. Lane o holds W[k][:,o] in registers.
// PPI = 64/FOUT pairs processed per iteration.
template <int FIN, int FOUT>
__global__ __launch_bounds__(64) void conv_kernel(
    const float* __restrict__ h, const float* __restrict__ W,
    const int* __restrict__ offsets, const int* __restrict__ pair_e,
    const float* __restrict__ pair_b, const int* __restrict__ ei,
    float* __restrict__ agg) {
    constexpr int PPI = 64 / FOUT;
    int k = blockIdx.x;
    int start = offsets[k], end = offsets[k + 1];
    if (start >= end) return;
    int lane = threadIdx.x;
    int g = lane / FOUT;
    int o = lane % FOUT;
    const float* Wk = W + (size_t)k * (FIN * FOUT);
    float w[FIN];
#pragma unroll
    for (int i = 0; i < FIN; ++i) w[i] = Wk[i * FOUT + o];
    __shared__ float xsh[PPI][FIN];
    for (int p = start; p < end; p += PPI) {
        int pp = p + g;
        bool valid = (pp < end);
        int psafe = valid ? pp : start;
        int e = pair_e[psafe];
        float b = valid ? pair_b[psafe] : 0.0f;
        int src = ei[e];
        int dst = ei[EV + e];
        __syncthreads();
        for (int i = o; i < FIN; i += FOUT) xsh[g][i] = h[src * FIN + i];
        __syncthreads();
        float acc = 0.0f;
#pragma unroll
        for (int i = 0; i < FIN; ++i) acc += xsh[g][i] * w[i];
        if (valid) atomicAdd(&agg[(size_t)dst * FOUT + o], b * acc);
    }
}

// FOUT=1 special case (layer 5): one lane per pair.
__global__ __launch_bounds__(64) void conv_kernel_f1(
    const float* __restrict__ h, const float* __restrict__ W,
    const int* __restrict__ offsets, const int* __restrict__ pair_e,
    const float* __restrict__ pair_b, const int* __restrict__ ei,
    float* __restrict__ agg) {
    int k = blockIdx.x;
    int start = offsets[k], end = offsets[k + 1];
    if (start >= end) return;
    int lane = threadIdx.x;
    const float* Wk = W + (size_t)k * 32;
    float w[32];
#pragma unroll
    for (int i = 0; i < 32; ++i) w[i] = Wk[i];
    for (int pp = start + lane; pp < end; pp += 64) {
        int e = pair_e[pp];
        float b = pair_b[pp];
        int src = ei[e];
        int dst = ei[EV + e];
        float acc = 0.0f;
#pragma unroll
        for (int i = 0; i < 32; ++i) acc += h[src * 32 + i] * w[i];
        atomicAdd(&agg[dst], b * acc);
    }
}

template <int FIN, int FOUT>
__global__ void node_kernel(const float* __restrict__ h, const float* __restrict__ agg,
                            const float* __restrict__ root, const float* __restrict__ bias,
                            float* __restrict__ hout) {
    int idx = blockIdx.x * blockDim.x + threadIdx.x;
    if (idx >= NV * FOUT) return;
    int n = idx / FOUT, o = idx % FOUT;
    float acc = agg[idx] + bias[o];
#pragma unroll
    for (int i = 0; i < FIN; ++i) acc += h[n * FIN + i] * root[i * FOUT + o];
    hout[idx] = acc > 0.0f ? acc : expm1f(acc);
}

extern "C" void kernel_launch(void* const* d_in, const int* in_sizes, int n_in,
                              void* d_out, int out_size, void* d_ws, size_t ws_size,
                              hipStream_t stream) {
    const float* x      = (const float*)d_in[0];
    const int*   ei     = (const int*)d_in[1];
    const float* pseudo = (const float*)d_in[2];
    const float* W1 = (const float*)d_in[3];
    const float* r1 = (const float*)d_in[4];
    const float* b1 = (const float*)d_in[5];
    const float* W2 = (const float*)d_in[6];
    const float* r2 = (const float*)d_in[7];
    const float* b2 = (const float*)d_in[8];
    const float* W3 = (const float*)d_in[9];
    const float* r3 = (const float*)d_in[10];
    const float* b3 = (const float*)d_in[11];
    const float* W4 = (const float*)d_in[12];
    const float* r4 = (const float*)d_in[13];
    const float* b4 = (const float*)d_in[14];
    const float* W5 = (const float*)d_in[15];
    const float* r5 = (const float*)d_in[16];
    const float* b5 = (const float*)d_in[17];

    char* ws = (char*)d_ws;
    size_t off = 0;
    auto alloc = [&](size_t bytes) {
        void* p = ws + off;
        off += (bytes + 255) & ~(size_t)255;
        return p;
    };
    int*   counts  = (int*)alloc(KK * sizeof(int));
    int*   offsets = (int*)alloc((KK + 1) * sizeof(int));
    int*   cursor  = (int*)alloc(KK * sizeof(int));
    int*   pair_e  = (int*)alloc((size_t)EV * 8 * sizeof(int));
    float* pair_b  = (float*)alloc((size_t)EV * 8 * sizeof(float));
    float* hA      = (float*)alloc((size_t)NV * 64 * sizeof(float));
    float* hB      = (float*)alloc((size_t)NV * 64 * sizeof(float));
    float* agg     = (float*)alloc((size_t)NV * 64 * sizeof(float));

    hipMemsetAsync(counts, 0, KK * sizeof(int), stream);
    transform_kernel<<<(NV + 255) / 256, 256, 0, stream>>>(x, hA);
    hist_kernel<<<(EV + 255) / 256, 256, 0, stream>>>(pseudo, counts);
    scan_kernel<<<1, 256, 0, stream>>>(counts, offsets, cursor);
    scatter_kernel<<<(EV + 255) / 256, 256, 0, stream>>>(pseudo, cursor, pair_e, pair_b);

    // Layer 1: [N,2] -> [N,32]   (hA -> hB)
    hipMemsetAsync(agg, 0, (size_t)NV * 32 * sizeof(float), stream);
    conv_kernel<2, 32><<<KK, 64, 0, stream>>>(hA, W1, offsets, pair_e, pair_b, ei, agg);
    node_kernel<2, 32><<<(NV * 32 + 255) / 256, 256, 0, stream>>>(hA, agg, r1, b1, hB);

    // Layer 2: [N,32] -> [N,64]  (hB -> hA)
    hipMemsetAsync(agg, 0, (size_t)NV * 64 * sizeof(float), stream);
    conv_kernel<32, 64><<<KK, 64, 0, stream>>>(hB, W2, offsets, pair_e, pair_b, ei, agg);
    node_kernel<32, 64><<<(NV * 64 + 255) / 256, 256, 0, stream>>>(hB, agg, r2, b2, hA);

    // Layer 3: [N,64] -> [N,64]  (hA -> hB)
    hipMemsetAsync(agg, 0, (size_t)NV * 64 * sizeof(float), stream);
    conv_kernel<64, 64><<<KK, 64, 0, stream>>>(hA, W3, offsets, pair_e, pair_b, ei, agg);
    node_kernel<64, 64><<<(NV * 64 + 255) / 256, 256, 0, stream>>>(hA, agg, r3, b3, hB);

    // Layer 4: [N,64] -> [N,32]  (hB -> hA)
    hipMemsetAsync(agg, 0, (size_t)NV * 32 * sizeof(float), stream);
    conv_kernel<64, 32><<<KK, 64, 0, stream>>>(hB, W4, offsets, pair_e, pair_b, ei, agg);
    node_kernel<64, 32><<<(NV * 32 + 255) / 256, 256, 0, stream>>>(hB, agg, r4, b4, hA);

    // Layer 5: [N,32] -> [N,1]   (hA -> d_out)
    hipMemsetAsync(agg, 0, (size_t)NV * sizeof(float), stream);
    conv_kernel_f1<<<KK, 64, 0, stream>>>(hA, W5, offsets, pair_e, pair_b, ei, agg);
    node_kernel<32, 1><<<(NV + 255) / 256, 256, 0, stream>>>(hA, agg, r5, b5, (float*)d_out);
}

// Round 2
// 611.179 us; speedup vs baseline: 1.0017x; 1.0017x over previous
//
#include <hip/hip_runtime.h>
#include <math.h>

// Problem constants (match reference)
#define NV 8192
#define EV 49152
#define KK 15625

__device__ __forceinline__ void edge_frac(const float* __restrict__ pseudo, int e,
                                          float f[3], int lo[3]) {
#pragma unroll
    for (int j = 0; j < 3; ++j) {
        float v = pseudo[e * 3 + j] * 24.0f;
        float fl = floorf(v);
        int l = (int)fl;
        l = l < 0 ? 0 : (l > 23 ? 23 : l);
        lo[j] = l;
        f[j] = v - (float)l;
    }
}

__global__ void transform_kernel(const float* __restrict__ x, float* __restrict__ h0) {
    int n = blockIdx.x * blockDim.x + threadIdx.x;
    if (n >= NV) return;
    const float LC = -0.22703196f, UC = 0.36853024f;
    const float LM = 1.2585511f, UM = 1.648841f;
    const float R = 10.0f;
    float t0 = (x[n * 2 + 0] - LC) / (UC - LC) * (2.0f * R) - R;
    float t1 = (x[n * 2 + 1] - LM) / (UM - LM) * (2.0f * R) - R;
    h0[n * 2 + 0] = fminf(fmaxf(t0, -R), R);
    h0[n * 2 + 1] = fminf(fmaxf(t1, -R), R);
}

__global__ void hist_kernel(const float* __restrict__ pseudo, int* __restrict__ counts) {
    int e = blockIdx.x * blockDim.x + threadIdx.x;
    if (e >= EV) return;
    float f[3]; int lo[3];
    edge_frac(pseudo, e, f, lo);
#pragma unroll
    for (int s = 0; s < 8; ++s) {
        int wi = (lo[0] + (s & 1)) + 25 * (lo[1] + ((s >> 1) & 1)) + 625 * (lo[2] + ((s >> 2) & 1));
        atomicAdd(&counts[wi], 1);
    }
}

// single-block exclusive scan over KK bins
__global__ void scan_kernel(const int* __restrict__ counts, int* __restrict__ offsets,
                            int* __restrict__ cursor) {
    __shared__ int sums[256];
    const int CH = 62;  // 256*62 = 15872 >= 15625
    int t = threadIdx.x;
    int base = t * CH;
    int s = 0;
    for (int i = 0; i < CH; ++i) {
        int idx = base + i;
        if (idx < KK) s += counts[idx];
    }
    sums[t] = s;
    __syncthreads();
    for (int d = 1; d < 256; d <<= 1) {
        int v = (t >= d) ? sums[t - d] : 0;
        __syncthreads();
        sums[t] += v;
        __syncthreads();
    }
    int run = (t > 0) ? sums[t - 1] : 0;
    for (int i = 0; i < CH; ++i) {
        int idx = base + i;
        if (idx < KK) {
            offsets[idx] = run;
            cursor[idx] = run;
            run += counts[idx];
        }
    }
    if (t == 255) offsets[KK] = run;
}

__global__ void scatter_kernel(const float* __restrict__ pseudo, int* __restrict__ cursor,
                               int* __restrict__ pair_e, float* __restrict__ pair_b) {
    int e = blockIdx.x * blockDim.x + threadIdx.x;
    if (e >= EV) return;
    float f[3]; int lo[3];
    edge_frac(pseudo, e, f, lo);
#pragma unroll
    for (int s = 0; s < 8; ++s) {
        float b = ((s & 1) ? f[0] : 1.0f - f[0]) *
                  (((s >> 1) & 1) ? f[1] : 1.0f - f[1]) *
                  (((s >> 2) & 1) ? f[2] : 1.0f - f[2]);
        int wi = (lo[0] + (s & 1)) + 25 * (lo[1] + ((s >> 1) & 1)) + 625 * (lo[2] + ((s >> 2) & 1));
        int pos = atomicAdd(&cursor[wi], 1);
        pair_e[pos] = e;
        pair_b[pos] = b;
    }
}

// Conv v2: one kernel-index k per 256-thread block (4 waves).
// Wave w processes pairs start + w*PPI + g, strided by 4*PPI.
// Lane o of each group holds W[k][:,o] in registers; x rows staged in
// per-wave-private LDS (intra-wave DS ordering, no __syncthreads in loop).
template <int FIN, int FOUT>
__global__ __launch_bounds__(256) void conv_v2(
    const float* __restrict__ h, const float* __restrict__ W,
    const int* __restrict__ offsets, const int* __restrict__ pair_e,
    const float* __restrict__ pair_b, const int* __restrict__ ei,
    float* __restrict__ agg) {
    constexpr int PPI = 64 / FOUT;   // pairs per wave-iteration
    constexpr int STRIDE = 4 * PPI;  // pairs per block-iteration
    constexpr int NL4 = FIN / 4;     // float4 per x-row (NL4 <= FOUT required)
    int k = blockIdx.x;
    int start = offsets[k], end = offsets[k + 1];
    if (start >= end) return;
    int t = threadIdx.x;
    int w = t >> 6;
    int lane = t & 63;
    int g = lane / FOUT;
    int o = lane % FOUT;
    const float* Wk = W + (size_t)k * (FIN * FOUT);
    float wreg[FIN];
#pragma unroll
    for (int i = 0; i < FIN; ++i) wreg[i] = Wk[i * FOUT + o];
    __shared__ float4 xsh[4][PPI][NL4];

    for (int p0 = start + w * PPI; p0 < end; p0 += STRIDE) {
        int pp = p0 + g;
        bool valid = (pp < end);
        int psafe = valid ? pp : start;
        int e = pair_e[psafe];
        float b = pair_b[psafe];
        int src = ei[e];
        int dst = ei[EV + e];
        if (o < NL4) xsh[w][g][o] = ((const float4*)h)[(size_t)src * NL4 + o];
        __builtin_amdgcn_wave_barrier();  // keep DS write->read ordered in sched
        float a0 = 0.0f, a1 = 0.0f, a2 = 0.0f, a3 = 0.0f;
#pragma unroll
        for (int i4 = 0; i4 < NL4; ++i4) {
            float4 xv = xsh[w][g][i4];
            a0 += xv.x * wreg[4 * i4 + 0];
            a1 += xv.y * wreg[4 * i4 + 1];
            a2 += xv.z * wreg[4 * i4 + 2];
            a3 += xv.w * wreg[4 * i4 + 3];
        }
        __builtin_amdgcn_wave_barrier();
        if (valid) atomicAdd(&agg[(size_t)dst * FOUT + o], b * ((a0 + a1) + (a2 + a3)));
    }
}

// Layer 1 (FIN=2, FOUT=32): x row is 2 floats — read directly (broadcast), no LDS.
__global__ __launch_bounds__(256) void conv_l1(
    const float* __restrict__ h, const float* __restrict__ W,
    const int* __restrict__ offsets, const int* __restrict__ pair_e,
    const float* __restrict__ pair_b, const int* __restrict__ ei,
    float* __restrict__ agg) {
    constexpr int FOUT = 32, PPI = 2, STRIDE = 8;
    int k = blockIdx.x;
    int start = offsets[k], end = offsets[k + 1];
    if (start >= end) return;
    int t = threadIdx.x;
    int w = t >> 6;
    int lane = t & 63;
    int g = lane / FOUT;
    int o = lane % FOUT;
    const float* Wk = W + (size_t)k * 64;
    float w0 = Wk[o], w1 = Wk[32 + o];
    for (int p0 = start + w * PPI; p0 < end; p0 += STRIDE) {
        int pp = p0 + g;
        bool valid = (pp < end);
        int psafe = valid ? pp : start;
        int e = pair_e[psafe];
        float b = pair_b[psafe];
        int src = ei[e];
        int dst = ei[EV + e];
        float x0 = h[src * 2 + 0];
        float x1 = h[src * 2 + 1];
        if (valid) atomicAdd(&agg[(size_t)dst * FOUT + o], b * (x0 * w0 + x1 * w1));
    }
}

// FOUT=1 special case (layer 5): one lane per pair.
__global__ __launch_bounds__(64) void conv_kernel_f1(
    const float* __restrict__ h, const float* __restrict__ W,
    const int* __restrict__ offsets, const int* __restrict__ pair_e,
    const float* __restrict__ pair_b, const int* __restrict__ ei,
    float* __restrict__ agg) {
    int k = blockIdx.x;
    int start = offsets[k], end = offsets[k + 1];
    if (start >= end) return;
    int lane = threadIdx.x;
    const float* Wk = W + (size_t)k * 32;
    float w[32];
#pragma unroll
    for (int i = 0; i < 32; ++i) w[i] = Wk[i];
    for (int pp = start + lane; pp < end; pp += 64) {
        int e = pair_e[pp];
        float b = pair_b[pp];
        int src = ei[e];
        int dst = ei[EV + e];
        float acc = 0.0f;
#pragma unroll
        for (int i = 0; i < 32; ++i) acc += h[src * 32 + i] * w[i];
        atomicAdd(&agg[dst], b * acc);
    }
}

template <int FIN, int FOUT>
__global__ void node_kernel(const float* __restrict__ h, const float* __restrict__ agg,
                            const float* __restrict__ root, const float* __restrict__ bias,
                            float* __restrict__ hout) {
    int idx = blockIdx.x * blockDim.x + threadIdx.x;
    if (idx >= NV * FOUT) return;
    int n = idx / FOUT, o = idx % FOUT;
    float acc = agg[idx] + bias[o];
#pragma unroll
    for (int i = 0; i < FIN; ++i) acc += h[n * FIN + i] * root[i * FOUT + o];
    hout[idx] = acc > 0.0f ? acc : expm1f(acc);
}

extern "C" void kernel_launch(void* const* d_in, const int* in_sizes, int n_in,
                              void* d_out, int out_size, void* d_ws, size_t ws_size,
                              hipStream_t stream) {
    const float* x      = (const float*)d_in[0];
    const int*   ei     = (const int*)d_in[1];
    const float* pseudo = (const float*)d_in[2];
    const float* W1 = (const float*)d_in[3];
    const float* r1 = (const float*)d_in[4];
    const float* b1 = (const float*)d_in[5];
    const float* W2 = (const float*)d_in[6];
    const float* r2 = (const float*)d_in[7];
    const float* b2 = (const float*)d_in[8];
    const float* W3 = (const float*)d_in[9];
    const float* r3 = (const float*)d_in[10];
    const float* b3 = (const float*)d_in[11];
    const float* W4 = (const float*)d_in[12];
    const float* r4 = (const float*)d_in[13];
    const float* b4 = (const float*)d_in[14];
    const float* W5 = (const float*)d_in[15];
    const float* r5 = (const float*)d_in[16];
    const float* b5 = (const float*)d_in[17];

    char* ws = (char*)d_ws;
    size_t off = 0;
    auto alloc = [&](size_t bytes) {
        void* p = ws + off;
        off += (bytes + 255) & ~(size_t)255;
        return p;
    };
    int*   counts  = (int*)alloc(KK * sizeof(int));
    int*   offsets = (int*)alloc((KK + 1) * sizeof(int));
    int*   cursor  = (int*)alloc(KK * sizeof(int));
    int*   pair_e  = (int*)alloc((size_t)EV * 8 * sizeof(int));
    float* pair_b  = (float*)alloc((size_t)EV * 8 * sizeof(float));
    float* hA      = (float*)alloc((size_t)NV * 64 * sizeof(float));
    float* hB      = (float*)alloc((size_t)NV * 64 * sizeof(float));
    float* agg     = (float*)alloc((size_t)NV * 64 * sizeof(float));

    hipMemsetAsync(counts, 0, KK * sizeof(int), stream);
    transform_kernel<<<(NV + 255) / 256, 256, 0, stream>>>(x, hA);
    hist_kernel<<<(EV + 255) / 256, 256, 0, stream>>>(pseudo, counts);
    scan_kernel<<<1, 256, 0, stream>>>(counts, offsets, cursor);
    scatter_kernel<<<(EV + 255) / 256, 256, 0, stream>>>(pseudo, cursor, pair_e, pair_b);

    // Layer 1: [N,2] -> [N,32]   (hA -> hB)
    hipMemsetAsync(agg, 0, (size_t)NV * 32 * sizeof(float), stream);
    conv_l1<<<KK, 256, 0, stream>>>(hA, W1, offsets, pair_e, pair_b, ei, agg);
    node_kernel<2, 32><<<(NV * 32 + 255) / 256, 256, 0, stream>>>(hA, agg, r1, b1, hB);

    // Layer 2: [N,32] -> [N,64]  (hB -> hA)
    hipMemsetAsync(agg, 0, (size_t)NV * 64 * sizeof(float), stream);
    conv_v2<32, 64><<<KK, 256, 0, stream>>>(hB, W2, offsets, pair_e, pair_b, ei, agg);
    node_kernel<32, 64><<<(NV * 64 + 255) / 256, 256, 0, stream>>>(hB, agg, r2, b2, hA);

    // Layer 3: [N,64] -> [N,64]  (hA -> hB)
    hipMemsetAsync(agg, 0, (size_t)NV * 64 * sizeof(float), stream);
    conv_v2<64, 64><<<KK, 256, 0, stream>>>(hA, W3, offsets, pair_e, pair_b, ei, agg);
    node_kernel<64, 64><<<(NV * 64 + 255) / 256, 256, 0, stream>>>(hA, agg, r3, b3, hB);

    // Layer 4: [N,64] -> [N,32]  (hB -> hA)
    hipMemsetAsync(agg, 0, (size_t)NV * 32 * sizeof(float), stream);
    conv_v2<64, 32><<<KK, 256, 0, stream>>>(hB, W4, offsets, pair_e, pair_b, ei, agg);
    node_kernel<64, 32><<<(NV * 32 + 255) / 256, 256, 0, stream>>>(hB, agg, r4, b4, hA);

    // Layer 5: [N,32] -> [N,1]   (hA -> d_out)
    hipMemsetAsync(agg, 0, (size_t)NV * sizeof(float), stream);
    conv_kernel_f1<<<KK, 64, 0, stream>>>(hA, W5, offsets, pair_e, pair_b, ei, agg);
    node_kernel<32, 1><<<(NV + 255) / 256, 256, 0, stream>>>(hA, agg, r5, b5, (float*)d_out);
}

// Round 3
// 515.912 us; speedup vs baseline: 1.1867x; 1.1847x over previous
//
#include <hip/hip_runtime.h>
#include <math.h>

// Problem constants (match reference)
#define NV 8192
#define EV 49152
#define KK 15625

__device__ __forceinline__ void edge_frac(const float* __restrict__ pseudo, int e,
                                          float f[3], int lo[3]) {
#pragma unroll
    for (int j = 0; j < 3; ++j) {
        float v = pseudo[e * 3 + j] * 24.0f;
        float fl = floorf(v);
        int l = (int)fl;
        l = l < 0 ? 0 : (l > 23 ? 23 : l);
        lo[j] = l;
        f[j] = v - (float)l;
    }
}

__global__ void transform_kernel(const float* __restrict__ x, float* __restrict__ h0) {
    int n = blockIdx.x * blockDim.x + threadIdx.x;
    if (n >= NV) return;
    const float LC = -0.22703196f, UC = 0.36853024f;
    const float LM = 1.2585511f, UM = 1.648841f;
    const float R = 10.0f;
    float t0 = (x[n * 2 + 0] - LC) / (UC - LC) * (2.0f * R) - R;
    float t1 = (x[n * 2 + 1] - LM) / (UM - LM) * (2.0f * R) - R;
    h0[n * 2 + 0] = fminf(fmaxf(t0, -R), R);
    h0[n * 2 + 1] = fminf(fmaxf(t1, -R), R);
}

__global__ void hist_kernel(const float* __restrict__ pseudo, int* __restrict__ counts) {
    int e = blockIdx.x * blockDim.x + threadIdx.x;
    if (e >= EV) return;
    float f[3]; int lo[3];
    edge_frac(pseudo, e, f, lo);
#pragma unroll
    for (int s = 0; s < 8; ++s) {
        int wi = (lo[0] + (s & 1)) + 25 * (lo[1] + ((s >> 1) & 1)) + 625 * (lo[2] + ((s >> 2) & 1));
        atomicAdd(&counts[wi], 1);
    }
}

// single-block exclusive scan over KK bins
__global__ void scan_kernel(const int* __restrict__ counts, int* __restrict__ offsets,
                            int* __restrict__ cursor) {
    __shared__ int sums[256];
    const int CH = 62;  // 256*62 = 15872 >= 15625
    int t = threadIdx.x;
    int base = t * CH;
    int s = 0;
    for (int i = 0; i < CH; ++i) {
        int idx = base + i;
        if (idx < KK) s += counts[idx];
    }
    sums[t] = s;
    __syncthreads();
    for (int d = 1; d < 256; d <<= 1) {
        int v = (t >= d) ? sums[t - d] : 0;
        __syncthreads();
        sums[t] += v;
        __syncthreads();
    }
    int run = (t > 0) ? sums[t - 1] : 0;
    for (int i = 0; i < CH; ++i) {
        int idx = base + i;
        if (idx < KK) {
            offsets[idx] = run;
            cursor[idx] = run;
            run += counts[idx];
        }
    }
    if (t == 255) offsets[KK] = run;
}

// Store (src, b) and dst per sorted pair: removes the pair->edge->node indirection
// from the conv kernels' critical path.
__global__ void scatter_kernel(const float* __restrict__ pseudo, const int* __restrict__ ei,
                               int* __restrict__ cursor,
                               int2* __restrict__ pair_sb, int* __restrict__ pair_dst) {
    int e = blockIdx.x * blockDim.x + threadIdx.x;
    if (e >= EV) return;
    float f[3]; int lo[3];
    edge_frac(pseudo, e, f, lo);
    int src = ei[e];
    int dst = ei[EV + e];
#pragma unroll
    for (int s = 0; s < 8; ++s) {
        float b = ((s & 1) ? f[0] : 1.0f - f[0]) *
                  (((s >> 1) & 1) ? f[1] : 1.0f - f[1]) *
                  (((s >> 2) & 1) ? f[2] : 1.0f - f[2]);
        int wi = (lo[0] + (s & 1)) + 25 * (lo[1] + ((s >> 1) & 1)) + 625 * (lo[2] + ((s >> 2) & 1));
        int pos = atomicAdd(&cursor[wi], 1);
        pair_sb[pos] = make_int2(src, __float_as_int(b));
        pair_dst[pos] = dst;
    }
}

// Conv v3: one WAVE per kernel-index k (4 buckets per 256-thread block).
// W[k] register-resident (lane o holds column o). Pairs staged in panels of
// P=16 rows into wave-private LDS, pre-scaled by b, double-buffered so the
// next panel's global loads issue before the current panel's compute.
// No __syncthreads anywhere (waves fully independent).
template <int FIN, int FOUT>
__global__ __launch_bounds__(256) void conv_v3(
    const float* __restrict__ h, const float* __restrict__ W,
    const int* __restrict__ offsets, const int2* __restrict__ pair_sb,
    const int* __restrict__ pair_dst, float* __restrict__ agg) {
    constexpr int P = 16;            // panel rows
    constexpr int C4 = FIN / 4;      // float4 chunks per row (8 or 16)
    constexpr int J = C4 / 4;        // chunks staged per lane (2 or 4)
    constexpr int RG = 64 / FOUT;    // rows computed per inner step (1 or 2)
    int w = threadIdx.x >> 6;
    int lane = threadIdx.x & 63;
    int k = blockIdx.x * 4 + w;
    if (k >= KK) return;
    int start = offsets[k];
    int n = offsets[k + 1] - start;
    if (n <= 0) return;
    int o = lane % FOUT;
    int g = lane / FOUT;
    const float* Wk = W + (size_t)k * (FIN * FOUT);
    float wreg[FIN];
#pragma unroll
    for (int i = 0; i < FIN; ++i) wreg[i] = Wk[i * FOUT + o];

    __shared__ float4 xsh[4][2][P][C4];
    int sr = lane >> 2;   // staging row (4 lanes per row)
    int sc = lane & 3;    // staging chunk base

    const float4* h4 = (const float4*)h;

    float4 v[J];
    auto ldpanel = [&](int p0) {
        int pp = p0 + sr;
        int2 sb = (pp < n) ? pair_sb[start + pp] : make_int2(0, 0);
        float b = __int_as_float(sb.y);  // invalid rows: b = +0.0f -> zero row
        const float4* hr = h4 + (size_t)sb.x * C4;
#pragma unroll
        for (int j = 0; j < J; ++j) {
            float4 t = hr[sc + 4 * j];
            v[j] = make_float4(t.x * b, t.y * b, t.z * b, t.w * b);
        }
    };
    auto stpanel = [&](int buf) {
#pragma unroll
        for (int j = 0; j < J; ++j) xsh[w][buf][sr][sc + 4 * j] = v[j];
    };
    auto cpanel = [&](int buf, int p0) {
        int lim = n - p0;
        if (lim > P) lim = P;
        for (int r = g; r < lim; r += RG) {
            int dst = pair_dst[start + p0 + r];
            float a0 = 0.0f, a1 = 0.0f, a2 = 0.0f, a3 = 0.0f;
#pragma unroll
            for (int i4 = 0; i4 < C4; ++i4) {
                float4 xv = xsh[w][buf][r][i4];
                a0 += xv.x * wreg[4 * i4 + 0];
                a1 += xv.y * wreg[4 * i4 + 1];
                a2 += xv.z * wreg[4 * i4 + 2];
                a3 += xv.w * wreg[4 * i4 + 3];
            }
            atomicAdd(&agg[(size_t)dst * FOUT + o], (a0 + a1) + (a2 + a3));
        }
    };

    int nP = (n + P - 1) / P;
    ldpanel(0);
    stpanel(0);
    for (int p = 0; p < nP; ++p) {
        int buf = p & 1;
        if (p + 1 < nP) ldpanel((p + 1) * P);   // issue next panel's loads early
        cpanel(buf, p * P);                      // compute current panel
        if (p + 1 < nP) stpanel(buf ^ 1);        // stage next panel
        __builtin_amdgcn_wave_barrier();
    }
}

// Layer 1 (FIN=2, FOUT=32): x row is 2 floats — direct loads, no staging.
__global__ __launch_bounds__(256) void conv_l1(
    const float* __restrict__ h, const float* __restrict__ W,
    const int* __restrict__ offsets, const int2* __restrict__ pair_sb,
    const int* __restrict__ pair_dst, float* __restrict__ agg) {
    int w = threadIdx.x >> 6;
    int lane = threadIdx.x & 63;
    int k = blockIdx.x * 4 + w;
    if (k >= KK) return;
    int start = offsets[k];
    int n = offsets[k + 1] - start;
    if (n <= 0) return;
    int o = lane & 31;
    int g = lane >> 5;
    const float* Wk = W + (size_t)k * 64;
    float w0 = Wk[o], w1 = Wk[32 + o];
    const float2* h2 = (const float2*)h;
    for (int r = g; r < n; r += 2) {
        int2 sb = pair_sb[start + r];
        float b = __int_as_float(sb.y);
        int dst = pair_dst[start + r];
        float2 xv = h2[sb.x];
        atomicAdd(&agg[(size_t)dst * 32 + o], b * (xv.x * w0 + xv.y * w1));
    }
}

// Layer 5 (FIN=32, FOUT=1): half-wave per row, shuffle reduce.
__global__ __launch_bounds__(256) void conv_f1(
    const float* __restrict__ h, const float* __restrict__ W,
    const int* __restrict__ offsets, const int2* __restrict__ pair_sb,
    const int* __restrict__ pair_dst, float* __restrict__ agg) {
    int w = threadIdx.x >> 6;
    int lane = threadIdx.x & 63;
    int k = blockIdx.x * 4 + w;
    if (k >= KK) return;
    int start = offsets[k];
    int n = offsets[k + 1] - start;
    if (n <= 0) return;
    int i = lane & 31;
    int g = lane >> 5;
    float wk = W[(size_t)k * 32 + i];
    for (int r = g; r < n; r += 2) {
        int2 sb = pair_sb[start + r];
        float b = __int_as_float(sb.y);
        int dst = pair_dst[start + r];
        float val = h[(size_t)sb.x * 32 + i] * wk * b;
#pragma unroll
        for (int d = 16; d >= 1; d >>= 1) val += __shfl_xor(val, d, 32);
        if (i == 0) atomicAdd(&agg[dst], val);
    }
}

template <int FIN, int FOUT>
__global__ void node_kernel(const float* __restrict__ h, const float* __restrict__ agg,
                            const float* __restrict__ root, const float* __restrict__ bias,
                            float* __restrict__ hout) {
    int idx = blockIdx.x * blockDim.x + threadIdx.x;
    if (idx >= NV * FOUT) return;
    int n = idx / FOUT, o = idx % FOUT;
    float acc = agg[idx] + bias[o];
#pragma unroll
    for (int i = 0; i < FIN; ++i) acc += h[n * FIN + i] * root[i * FOUT + o];
    hout[idx] = acc > 0.0f ? acc : expm1f(acc);
}

extern "C" void kernel_launch(void* const* d_in, const int* in_sizes, int n_in,
                              void* d_out, int out_size, void* d_ws, size_t ws_size,
                              hipStream_t stream) {
    const float* x      = (const float*)d_in[0];
    const int*   ei     = (const int*)d_in[1];
    const float* pseudo = (const float*)d_in[2];
    const float* W1 = (const float*)d_in[3];
    const float* r1 = (const float*)d_in[4];
    const float* b1 = (const float*)d_in[5];
    const float* W2 = (const float*)d_in[6];
    const float* r2 = (const float*)d_in[7];
    const float* b2 = (const float*)d_in[8];
    const float* W3 = (const float*)d_in[9];
    const float* r3 = (const float*)d_in[10];
    const float* b3 = (const float*)d_in[11];
    const float* W4 = (const float*)d_in[12];
    const float* r4 = (const float*)d_in[13];
    const float* b4 = (const float*)d_in[14];
    const float* W5 = (const float*)d_in[15];
    const float* r5 = (const float*)d_in[16];
    const float* b5 = (const float*)d_in[17];

    char* ws = (char*)d_ws;
    size_t off = 0;
    auto alloc = [&](size_t bytes) {
        void* p = ws + off;
        off += (bytes + 255) & ~(size_t)255;
        return p;
    };
    int*   counts   = (int*)alloc(KK * sizeof(int));
    int*   offsets  = (int*)alloc((KK + 1) * sizeof(int));
    int*   cursor   = (int*)alloc(KK * sizeof(int));
    int2*  pair_sb  = (int2*)alloc((size_t)EV * 8 * sizeof(int2));
    int*   pair_dst = (int*)alloc((size_t)EV * 8 * sizeof(int));
    float* hA       = (float*)alloc((size_t)NV * 64 * sizeof(float));
    float* hB       = (float*)alloc((size_t)NV * 64 * sizeof(float));
    float* agg      = (float*)alloc((size_t)NV * 64 * sizeof(float));

    const int CGRID = (KK + 3) / 4;  // 4 buckets (waves) per block

    hipMemsetAsync(counts, 0, KK * sizeof(int), stream);
    transform_kernel<<<(NV + 255) / 256, 256, 0, stream>>>(x, hA);
    hist_kernel<<<(EV + 255) / 256, 256, 0, stream>>>(pseudo, counts);
    scan_kernel<<<1, 256, 0, stream>>>(counts, offsets, cursor);
    scatter_kernel<<<(EV + 255) / 256, 256, 0, stream>>>(pseudo, ei, cursor, pair_sb, pair_dst);

    // Layer 1: [N,2] -> [N,32]   (hA -> hB)
    hipMemsetAsync(agg, 0, (size_t)NV * 32 * sizeof(float), stream);
    conv_l1<<<CGRID, 256, 0, stream>>>(hA, W1, offsets, pair_sb, pair_dst, agg);
    node_kernel<2, 32><<<(NV * 32 + 255) / 256, 256, 0, stream>>>(hA, agg, r1, b1, hB);

    // Layer 2: [N,32] -> [N,64]  (hB -> hA)
    hipMemsetAsync(agg, 0, (size_t)NV * 64 * sizeof(float), stream);
    conv_v3<32, 64><<<CGRID, 256, 0, stream>>>(hB, W2, offsets, pair_sb, pair_dst, agg);
    node_kernel<32, 64><<<(NV * 64 + 255) / 256, 256, 0, stream>>>(hB, agg, r2, b2, hA);

    // Layer 3: [N,64] -> [N,64]  (hA -> hB)
    hipMemsetAsync(agg, 0, (size_t)NV * 64 * sizeof(float), stream);
    conv_v3<64, 64><<<CGRID, 256, 0, stream>>>(hA, W3, offsets, pair_sb, pair_dst, agg);
    node_kernel<64, 64><<<(NV * 64 + 255) / 256, 256, 0, stream>>>(hA, agg, r3, b3, hB);

    // Layer 4: [N,64] -> [N,32]  (hB -> hA)
    hipMemsetAsync(agg, 0, (size_t)NV * 32 * sizeof(float), stream);
    conv_v3<64, 32><<<CGRID, 256, 0, stream>>>(hB, W4, offsets, pair_sb, pair_dst, agg);
    node_kernel<64, 32><<<(NV * 32 + 255) / 256, 256, 0, stream>>>(hB, agg, r4, b4, hA);

    // Layer 5: [N,32] -> [N,1]   (hA -> d_out)
    hipMemsetAsync(agg, 0, (size_t)NV * sizeof(float), stream);
    conv_f1<<<CGRID, 256, 0, stream>>>(hA, W5, offsets, pair_sb, pair_dst, agg);
    node_kernel<32, 1><<<(NV + 255) / 256, 256, 0, stream>>>(hA, agg, r5, b5, (float*)d_out);
}

// Round 4
// 509.894 us; speedup vs baseline: 1.2007x; 1.0118x over previous
//
#include <hip/hip_runtime.h>
#include <math.h>

// Problem constants (match reference)
#define NV 8192
#define EV 49152
#define KK 15625

typedef __attribute__((ext_vector_type(8))) short bf16x8;
typedef __attribute__((ext_vector_type(4))) float f32x4;

__device__ __forceinline__ unsigned short bf16rne(float x) {
    unsigned u = __float_as_uint(x);
    unsigned r = u + 0x7FFFu + ((u >> 16) & 1u);
    return (unsigned short)(r >> 16);
}
__device__ __forceinline__ float bf16tof(unsigned short h) {
    return __uint_as_float(((unsigned)h) << 16);
}

__device__ __forceinline__ void edge_frac(const float* __restrict__ pseudo, int e,
                                          float f[3], int lo[3]) {
#pragma unroll
    for (int j = 0; j < 3; ++j) {
        float v = pseudo[e * 3 + j] * 24.0f;
        float fl = floorf(v);
        int l = (int)fl;
        l = l < 0 ? 0 : (l > 23 ? 23 : l);
        lo[j] = l;
        f[j] = v - (float)l;
    }
}

__global__ void transform_kernel(const float* __restrict__ x, float* __restrict__ h0) {
    int n = blockIdx.x * blockDim.x + threadIdx.x;
    if (n >= NV) return;
    const float LC = -0.22703196f, UC = 0.36853024f;
    const float LM = 1.2585511f, UM = 1.648841f;
    const float R = 10.0f;
    float t0 = (x[n * 2 + 0] - LC) / (UC - LC) * (2.0f * R) - R;
    float t1 = (x[n * 2 + 1] - LM) / (UM - LM) * (2.0f * R) - R;
    h0[n * 2 + 0] = fminf(fmaxf(t0, -R), R);
    h0[n * 2 + 1] = fminf(fmaxf(t1, -R), R);
}

__global__ void hist_kernel(const float* __restrict__ pseudo, int* __restrict__ counts) {
    int e = blockIdx.x * blockDim.x + threadIdx.x;
    if (e >= EV) return;
    float f[3]; int lo[3];
    edge_frac(pseudo, e, f, lo);
#pragma unroll
    for (int s = 0; s < 8; ++s) {
        int wi = (lo[0] + (s & 1)) + 25 * (lo[1] + ((s >> 1) & 1)) + 625 * (lo[2] + ((s >> 2) & 1));
        atomicAdd(&counts[wi], 1);
    }
}

// single-block exclusive scan over KK bins
__global__ void scan_kernel(const int* __restrict__ counts, int* __restrict__ offsets,
                            int* __restrict__ cursor) {
    __shared__ int sums[256];
    const int CH = 62;  // 256*62 = 15872 >= 15625
    int t = threadIdx.x;
    int base = t * CH;
    int s = 0;
    for (int i = 0; i < CH; ++i) {
        int idx = base + i;
        if (idx < KK) s += counts[idx];
    }
    sums[t] = s;
    __syncthreads();
    for (int d = 1; d < 256; d <<= 1) {
        int v = (t >= d) ? sums[t - d] : 0;
        __syncthreads();
        sums[t] += v;
        __syncthreads();
    }
    int run = (t > 0) ? sums[t - 1] : 0;
    for (int i = 0; i < CH; ++i) {
        int idx = base + i;
        if (idx < KK) {
            offsets[idx] = run;
            cursor[idx] = run;
            run += counts[idx];
        }
    }
    if (t == 255) offsets[KK] = run;
}

// Store (src, b) and dst per sorted pair.
__global__ void scatter_kernel(const float* __restrict__ pseudo, const int* __restrict__ ei,
                               int* __restrict__ cursor,
                               int2* __restrict__ pair_sb, int* __restrict__ pair_dst) {
    int e = blockIdx.x * blockDim.x + threadIdx.x;
    if (e >= EV) return;
    float f[3]; int lo[3];
    edge_frac(pseudo, e, f, lo);
    int src = ei[e];
    int dst = ei[EV + e];
#pragma unroll
    for (int s = 0; s < 8; ++s) {
        float b = ((s & 1) ? f[0] : 1.0f - f[0]) *
                  (((s >> 1) & 1) ? f[1] : 1.0f - f[1]) *
                  (((s >> 2) & 1) ? f[2] : 1.0f - f[2]);
        int wi = (lo[0] + (s & 1)) + 25 * (lo[1] + ((s >> 1) & 1)) + 625 * (lo[2] + ((s >> 2) & 1));
        int pos = atomicAdd(&cursor[wi], 1);
        pair_sb[pos] = make_int2(src, __float_as_int(b));
        pair_dst[pos] = dst;
    }
}

// MFMA conv: one WAVE per kernel-index k (4 buckets per 256-thread block).
// Per bucket: C[n x FOUT] = (b .* X[src]) @ W[k], computed as 16x16x32 bf16
// MFMAs with two-term (hi+lo) bf16 splits of both operands (3 MFMAs per
// logical product -> ~f32 precision, f32 accumulate). No LDS.
// A-frag: lane l holds A[l&15][(l>>4)*8 + i], i=0..7 (per k-tile of 32).
// B-frag: lane l holds B[(l>>4)*8 + i][l&15].
// C/D  : lane l, reg j = D[(l>>4)*4 + j][l&15]  (HW-verified layout).
template <int FIN, int FOUT>
__global__ __launch_bounds__(256) void conv_mfma(
    const float* __restrict__ h, const float* __restrict__ W,
    const int* __restrict__ offsets, const int2* __restrict__ pair_sb,
    const int* __restrict__ pair_dst, float* __restrict__ agg) {
    constexpr int KT = FIN / 32;   // k-tiles
    constexpr int NT = FOUT / 16;  // n-tiles
    int w = threadIdx.x >> 6;
    int lane = threadIdx.x & 63;
    int k = blockIdx.x * 4 + w;
    if (k >= KK) return;
    int start = offsets[k];
    int n = offsets[k + 1] - start;
    if (n <= 0) return;
    int l15 = lane & 15;
    int lg = lane >> 4;  // 0..3

    // ---- B fragments from W[k] (hi+lo bf16 split) ----
    const float* Wk = W + (size_t)k * (FIN * FOUT);
    bf16x8 Bh[NT][KT], Bl[NT][KT];
#pragma unroll
    for (int n0 = 0; n0 < NT; ++n0)
#pragma unroll
        for (int k0 = 0; k0 < KT; ++k0)
#pragma unroll
            for (int i = 0; i < 8; ++i) {
                float wv = Wk[(size_t)(k0 * 32 + lg * 8 + i) * FOUT + n0 * 16 + l15];
                unsigned short hi = bf16rne(wv);
                unsigned short lo = bf16rne(wv - bf16tof(hi));
                Bh[n0][k0][i] = (short)hi;
                Bl[n0][k0][i] = (short)lo;
            }

    // ---- M-tile loop over pair rows ----
    for (int m0 = 0; m0 < n; m0 += 16) {
        int ra = m0 + l15;
        bool va = ra < n;
        int2 sb = pair_sb[start + (va ? ra : 0)];
        float b = va ? __int_as_float(sb.y) : 0.0f;
        const float* xr = h + (size_t)sb.x * FIN + lg * 8;

        f32x4 acc[NT];
#pragma unroll
        for (int n0 = 0; n0 < NT; ++n0) acc[n0] = (f32x4){0.f, 0.f, 0.f, 0.f};

#pragma unroll
        for (int k0 = 0; k0 < KT; ++k0) {
            float4 v0 = *(const float4*)(xr + k0 * 32);
            float4 v1 = *(const float4*)(xr + k0 * 32 + 4);
            float xv[8] = {v0.x * b, v0.y * b, v0.z * b, v0.w * b,
                           v1.x * b, v1.y * b, v1.z * b, v1.w * b};
            bf16x8 Ah, Al;
#pragma unroll
            for (int i = 0; i < 8; ++i) {
                unsigned short hi = bf16rne(xv[i]);
                unsigned short lo = bf16rne(xv[i] - bf16tof(hi));
                Ah[i] = (short)hi;
                Al[i] = (short)lo;
            }
#pragma unroll
            for (int n0 = 0; n0 < NT; ++n0) {
                acc[n0] = __builtin_amdgcn_mfma_f32_16x16x32_bf16(Ah, Bh[n0][k0], acc[n0], 0, 0, 0);
                acc[n0] = __builtin_amdgcn_mfma_f32_16x16x32_bf16(Ah, Bl[n0][k0], acc[n0], 0, 0, 0);
                acc[n0] = __builtin_amdgcn_mfma_f32_16x16x32_bf16(Al, Bh[n0][k0], acc[n0], 0, 0, 0);
            }
        }

        // ---- scatter: D[(lg*4+j)][l15] of each n-tile ----
#pragma unroll
        for (int j = 0; j < 4; ++j) {
            int rm = m0 + lg * 4 + j;
            if (rm < n) {
                int d = pair_dst[start + rm];
#pragma unroll
                for (int n0 = 0; n0 < NT; ++n0)
                    atomicAdd(&agg[(size_t)d * FOUT + n0 * 16 + l15], acc[n0][j]);
            }
        }
    }
}

// Layer 1 (FIN=2, FOUT=32): direct loads, no staging.
__global__ __launch_bounds__(256) void conv_l1(
    const float* __restrict__ h, const float* __restrict__ W,
    const int* __restrict__ offsets, const int2* __restrict__ pair_sb,
    const int* __restrict__ pair_dst, float* __restrict__ agg) {
    int w = threadIdx.x >> 6;
    int lane = threadIdx.x & 63;
    int k = blockIdx.x * 4 + w;
    if (k >= KK) return;
    int start = offsets[k];
    int n = offsets[k + 1] - start;
    if (n <= 0) return;
    int o = lane & 31;
    int g = lane >> 5;
    const float* Wk = W + (size_t)k * 64;
    float w0 = Wk[o], w1 = Wk[32 + o];
    const float2* h2 = (const float2*)h;
    for (int r = g; r < n; r += 2) {
        int2 sb = pair_sb[start + r];
        float b = __int_as_float(sb.y);
        int dst = pair_dst[start + r];
        float2 xv = h2[sb.x];
        atomicAdd(&agg[(size_t)dst * 32 + o], b * (xv.x * w0 + xv.y * w1));
    }
}

// Layer 5 (FIN=32, FOUT=1): half-wave per row, shuffle reduce.
__global__ __launch_bounds__(256) void conv_f1(
    const float* __restrict__ h, const float* __restrict__ W,
    const int* __restrict__ offsets, const int2* __restrict__ pair_sb,
    const int* __restrict__ pair_dst, float* __restrict__ agg) {
    int w = threadIdx.x >> 6;
    int lane = threadIdx.x & 63;
    int k = blockIdx.x * 4 + w;
    if (k >= KK) return;
    int start = offsets[k];
    int n = offsets[k + 1] - start;
    if (n <= 0) return;
    int i = lane & 31;
    int g = lane >> 5;
    float wk = W[(size_t)k * 32 + i];
    for (int r = g; r < n; r += 2) {
        int2 sb = pair_sb[start + r];
        float b = __int_as_float(sb.y);
        int dst = pair_dst[start + r];
        float val = h[(size_t)sb.x * 32 + i] * wk * b;
#pragma unroll
        for (int d = 16; d >= 1; d >>= 1) val += __shfl_xor(val, d, 32);
        if (i == 0) atomicAdd(&agg[dst], val);
    }
}

template <int FIN, int FOUT>
__global__ void node_kernel(const float* __restrict__ h, const float* __restrict__ agg,
                            const float* __restrict__ root, const float* __restrict__ bias,
                            float* __restrict__ hout) {
    int idx = blockIdx.x * blockDim.x + threadIdx.x;
    if (idx >= NV * FOUT) return;
    int n = idx / FOUT, o = idx % FOUT;
    float acc = agg[idx] + bias[o];
#pragma unroll
    for (int i = 0; i < FIN; ++i) acc += h[n * FIN + i] * root[i * FOUT + o];
    hout[idx] = acc > 0.0f ? acc : expm1f(acc);
}

extern "C" void kernel_launch(void* const* d_in, const int* in_sizes, int n_in,
                              void* d_out, int out_size, void* d_ws, size_t ws_size,
                              hipStream_t stream) {
    const float* x      = (const float*)d_in[0];
    const int*   ei     = (const int*)d_in[1];
    const float* pseudo = (const float*)d_in[2];
    const float* W1 = (const float*)d_in[3];
    const float* r1 = (const float*)d_in[4];
    const float* b1 = (const float*)d_in[5];
    const float* W2 = (const float*)d_in[6];
    const float* r2 = (const float*)d_in[7];
    const float* b2 = (const float*)d_in[8];
    const float* W3 = (const float*)d_in[9];
    const float* r3 = (const float*)d_in[10];
    const float* b3 = (const float*)d_in[11];
    const float* W4 = (const float*)d_in[12];
    const float* r4 = (const float*)d_in[13];
    const float* b4 = (const float*)d_in[14];
    const float* W5 = (const float*)d_in[15];
    const float* r5 = (const float*)d_in[16];
    const float* b5 = (const float*)d_in[17];

    char* ws = (char*)d_ws;
    size_t off = 0;
    auto alloc = [&](size_t bytes) {
        void* p = ws + off;
        off += (bytes + 255) & ~(size_t)255;
        return p;
    };
    int*   counts   = (int*)alloc(KK * sizeof(int));
    int*   offsets  = (int*)alloc((KK + 1) * sizeof(int));
    int*   cursor   = (int*)alloc(KK * sizeof(int));
    int2*  pair_sb  = (int2*)alloc((size_t)EV * 8 * sizeof(int2));
    int*   pair_dst = (int*)alloc((size_t)EV * 8 * sizeof(int));
    float* hA       = (float*)alloc((size_t)NV * 64 * sizeof(float));
    float* hB       = (float*)alloc((size_t)NV * 64 * sizeof(float));
    float* agg      = (float*)alloc((size_t)NV * 64 * sizeof(float));

    const int CGRID = (KK + 3) / 4;  // 4 buckets (waves) per block

    hipMemsetAsync(counts, 0, KK * sizeof(int), stream);
    transform_kernel<<<(NV + 255) / 256, 256, 0, stream>>>(x, hA);
    hist_kernel<<<(EV + 255) / 256, 256, 0, stream>>>(pseudo, counts);
    scan_kernel<<<1, 256, 0, stream>>>(counts, offsets, cursor);
    scatter_kernel<<<(EV + 255) / 256, 256, 0, stream>>>(pseudo, ei, cursor, pair_sb, pair_dst);

    // Layer 1: [N,2] -> [N,32]   (hA -> hB)
    hipMemsetAsync(agg, 0, (size_t)NV * 32 * sizeof(float), stream);
    conv_l1<<<CGRID, 256, 0, stream>>>(hA, W1, offsets, pair_sb, pair_dst, agg);
    node_kernel<2, 32><<<(NV * 32 + 255) / 256, 256, 0, stream>>>(hA, agg, r1, b1, hB);

    // Layer 2: [N,32] -> [N,64]  (hB -> hA)
    hipMemsetAsync(agg, 0, (size_t)NV * 64 * sizeof(float), stream);
    conv_mfma<32, 64><<<CGRID, 256, 0, stream>>>(hB, W2, offsets, pair_sb, pair_dst, agg);
    node_kernel<32, 64><<<(NV * 64 + 255) / 256, 256, 0, stream>>>(hB, agg, r2, b2, hA);

    // Layer 3: [N,64] -> [N,64]  (hA -> hB)
    hipMemsetAsync(agg, 0, (size_t)NV * 64 * sizeof(float), stream);
    conv_mfma<64, 64><<<CGRID, 256, 0, stream>>>(hA, W3, offsets, pair_sb, pair_dst, agg);
    node_kernel<64, 64><<<(NV * 64 + 255) / 256, 256, 0, stream>>>(hA, agg, r3, b3, hB);

    // Layer 4: [N,64] -> [N,32]  (hB -> hA)
    hipMemsetAsync(agg, 0, (size_t)NV * 32 * sizeof(float), stream);
    conv_mfma<64, 32><<<CGRID, 256, 0, stream>>>(hB, W4, offsets, pair_sb, pair_dst, agg);
    node_kernel<64, 32><<<(NV * 32 + 255) / 256, 256, 0, stream>>>(hB, agg, r4, b4, hA);

    // Layer 5: [N,32] -> [N,1]   (hA -> d_out)
    hipMemsetAsync(agg, 0, (size_t)NV * sizeof(float), stream);
    conv_f1<<<CGRID, 256, 0, stream>>>(hA, W5, offsets, pair_sb, pair_dst, agg);
    node_kernel<32, 1><<<(NV + 255) / 256, 256, 0, stream>>>(hA, agg, r5, b5, (float*)d_out);
}